// Round 18
// baseline (68.536 us; speedup 1.0000x reference)
//
#include <hip/hip_runtime.h>
#include <hip/hip_bf16.h>

#define C_DIM   320
#define N_SP    2304      // 48*48
#define NHEADS  8
#define DHEAD   40
#define GROUPS  32
#define CPG     10
#define BATCH   2
#define DPAD    64        // d padded for K=32 MFMA steps
#define VPAD    48        // v rows padded to 3x16 (row 40 = ones, 41..47 = 0)
#define W_ELEMS (C_DIM * C_DIM)   // 102400
#define NSPLIT  6
#define KVBLK   32
#define TILES_PER_SPLIT 12        // 2304/32/6 (EVEN -> 2x unroll)
#define PSLOTS  41                // 40 O + lsum (slot 40, produced by ones-row MFMA)

typedef __bf16 bf16x8 __attribute__((ext_vector_type(8)));
typedef __bf16 bf16x4 __attribute__((ext_vector_type(4)));
typedef __bf16 bf16x2 __attribute__((ext_vector_type(2)));
typedef float  f32x4  __attribute__((ext_vector_type(4)));

typedef const __attribute__((address_space(1))) void* gas_ptr;
typedef __attribute__((address_space(3))) void* las_ptr;

#define MFMA16(a, b, c) __builtin_amdgcn_mfma_f32_16x16x32_bf16((a), (b), (c), 0, 0, 0)

// Native 2^x: one v_exp_f32, no libm denormal fixups (|S| <= ~6 here).
#if __has_builtin(__builtin_amdgcn_exp2f)
#define EXP2(x) __builtin_amdgcn_exp2f(x)
#else
#define EXP2(x) __expf((x) * 0.6931471805599453f)
#endif

// -------------------------------------------------------------------------
// Staging helpers for 64-col bf16 tiles (row stride 640B in global).
// -------------------------------------------------------------------------
__device__ __forceinline__ void stage8(const char* gbase, char* lbase,
                                       int chunk, int lane)
{
    const int row = chunk * 8 + (lane >> 3);
    const int cs  = (lane & 7) * 16;
    __builtin_amdgcn_global_load_lds(
        (gas_ptr)(gbase + (size_t)row * (C_DIM * 2) + (cs ^ ((row & 7) << 4))),
        (las_ptr)(lbase + chunk * 1024 + lane * 16), 16, 0, 0);
}

__device__ __forceinline__ bf16x8 lds_frag(const char* lbase, int row, int cbyte)
{
    return *(const bf16x8*)(lbase + row * 128 + (cbyte ^ ((row & 7) << 4)));
}

// -------------------------------------------------------------------------
// prep: gn_part (0..511) + weight cvt (512..611) + Q/K/V pad init (612..755).
// -------------------------------------------------------------------------
__global__ __launch_bounds__(256) void prep_kernel(
    const float* __restrict__ x, float* __restrict__ partials,
    const float* __restrict__ Wq, const float* __restrict__ Wk,
    const float* __restrict__ Wv, const float* __restrict__ Wo,
    __bf16* __restrict__ Wqb, __bf16* __restrict__ Wkb,
    __bf16* __restrict__ Wvb, __bf16* __restrict__ Wob,
    __bf16* __restrict__ Qt, __bf16* __restrict__ Kt, __bf16* __restrict__ Vb)
{
    if (blockIdx.x < 512) {
        const int bid = blockIdx.x;
        const int bg = bid >> 3, p = bid & 7;
        const int b = bg >> 5, g = bg & 31;
        const float* xp = x + ((size_t)b * C_DIM + g * CPG) * N_SP + p * 288;
        const int tid = threadIdx.x;

        float sum = 0.f, sq = 0.f;
        #pragma unroll
        for (int c = 0; c < CPG; ++c) {
            for (int nl = tid; nl < 288; nl += 256) {
                const float v = xp[(size_t)c * N_SP + nl];
                sum += v; sq += v * v;
            }
        }
        #pragma unroll
        for (int off = 32; off; off >>= 1) {
            sum += __shfl_xor(sum, off);
            sq  += __shfl_xor(sq, off);
        }
        __shared__ float red[2][4];
        if ((tid & 63) == 0) { red[0][tid >> 6] = sum; red[1][tid >> 6] = sq; }
        __syncthreads();
        if (tid == 0) {
            partials[2 * bid]     = red[0][0] + red[0][1] + red[0][2] + red[0][3];
            partials[2 * bid + 1] = red[1][0] + red[1][1] + red[1][2] + red[1][3];
        }
    } else if (blockIdx.x < 612) {
        const int i = ((blockIdx.x - 512) * 256 + threadIdx.x) * 4;
        f32x4 a;
        bf16x4 o;
        a = *(const f32x4*)(Wq + i);
        #pragma unroll
        for (int e = 0; e < 4; ++e) o[e] = (__bf16)a[e];
        *(bf16x4*)(Wqb + i) = o;
        a = *(const f32x4*)(Wk + i);
        #pragma unroll
        for (int e = 0; e < 4; ++e) o[e] = (__bf16)a[e];
        *(bf16x4*)(Wkb + i) = o;
        a = *(const f32x4*)(Wv + i);
        #pragma unroll
        for (int e = 0; e < 4; ++e) o[e] = (__bf16)a[e];
        *(bf16x4*)(Wvb + i) = o;
        a = *(const f32x4*)(Wo + i);
        #pragma unroll
        for (int e = 0; e < 4; ++e) o[e] = (__bf16)a[e];
        *(bf16x4*)(Wob + i) = o;
    } else {
        const int t = (blockIdx.x - 612) * 256 + threadIdx.x;  // < 36864
        const bf16x8 z = {};
        __bf16* q = Qt + (size_t)t * DPAD + 40;
        __bf16* k = Kt + (size_t)t * DPAD + 40;
        *(bf16x8*)(q) = z; *(bf16x8*)(q + 8) = z; *(bf16x8*)(q + 16) = z;
        *(bf16x8*)(k) = z; *(bf16x8*)(k + 8) = z; *(bf16x8*)(k + 16) = z;
        const int bh = t / N_SP;
        const int rem = t - bh * N_SP;
        const int r = rem / 288, n8 = rem - r * 288;
        bf16x8 v = z;
        if (r == 0) {
            #pragma unroll
            for (int e = 0; e < 8; ++e) v[e] = (__bf16)1.0f;
        }
        *(bf16x8*)(Vb + ((size_t)bh * VPAD + 40 + r) * N_SP + n8 * 8) = v;
    }
}

// -------------------------------------------------------------------------
// GroupNorm pass 2: finalize + normalize + transposed bf16 write.
// -------------------------------------------------------------------------
__global__ __launch_bounds__(256) void gn_apply(
    const float* __restrict__ x,
    const float* __restrict__ gamma, const float* __restrict__ beta,
    const float* __restrict__ partials, __bf16* __restrict__ xn_t)
{
    const int bid = blockIdx.x;
    const int bg = bid >> 3, p = bid & 7;
    const int b = bg >> 5, g = bg & 31;
    const int c0 = g * CPG;

    float sum = 0.f, sq = 0.f;
    #pragma unroll
    for (int i = 0; i < 8; ++i) {
        sum += partials[(bg * 8 + i) * 2];
        sq  += partials[(bg * 8 + i) * 2 + 1];
    }
    const float inv_n = 1.0f / (float)(CPG * N_SP);
    const float mean = sum * inv_n;
    const float rstd = rsqrtf(sq * inv_n - mean * mean + 1e-5f);

    float ga[CPG], be[CPG];
    #pragma unroll
    for (int c = 0; c < CPG; ++c) {
        ga[c] = gamma[c0 + c] * rstd;
        be[c] = beta[c0 + c] - mean * ga[c];
    }

    const float* xp = x + ((size_t)b * C_DIM + c0) * N_SP + p * 288;
    for (int nl = threadIdx.x; nl < 288; nl += 256) {
        const int n = p * 288 + nl;
        __bf16* dst = xn_t + ((size_t)b * N_SP + n) * C_DIM + c0;
        #pragma unroll
        for (int j = 0; j < CPG / 2; ++j) {
            const float v0 = xp[(size_t)(2 * j) * N_SP + nl]     * ga[2 * j]     + be[2 * j];
            const float v1 = xp[(size_t)(2 * j + 1) * N_SP + nl] * ga[2 * j + 1] + be[2 * j + 1];
            bf16x2 t; t[0] = (__bf16)v0; t[1] = (__bf16)v1;
            *(bf16x2*)(dst + 2 * j) = t;
        }
    }
}

// -------------------------------------------------------------------------
// Fused QKV projection, LDS-staged double-buffered K-loop.
// -------------------------------------------------------------------------
__global__ __launch_bounds__(256) void gemm_qkv(
    const __bf16* __restrict__ Wqb, const __bf16* __restrict__ Wkb, const __bf16* __restrict__ Wvb,
    const float* __restrict__ bq, const float* __restrict__ bk, const float* __restrict__ bv,
    const __bf16* __restrict__ Xt,
    __bf16* __restrict__ Qt, __bf16* __restrict__ Kt, __bf16* __restrict__ Vb)
{
    __shared__ __align__(16) char Ws[2][64 * 128];   // 2 x 8KB
    __shared__ __align__(16) char Xs[2][64 * 128];   // 2 x 8KB

    const int z = blockIdx.z;
    const int b = z / 3;
    const int which = z - 3 * b;
    const __bf16* W   = (which == 0) ? Wqb : (which == 1) ? Wkb : Wvb;
    const float* bias = (which == 0) ? bq : (which == 1) ? bk : bv;
    const float scale = (which == 0) ? 0.15811388300841897f
                      : (which == 1) ? 0.22811243f : 1.0f;

    const int n0 = blockIdx.x * 64, o0 = blockIdx.y * 64;
    const int tid = threadIdx.x, wave = tid >> 6, lane = tid & 63;
    const int lr = lane & 15, lk = lane >> 4;
    const int wm = wave >> 1, wn = wave & 1;

    const char* Wg = (const char*)(W + (size_t)o0 * C_DIM);
    const char* Xg = (const char*)(Xt + ((size_t)b * N_SP + n0) * C_DIM);

    auto stage = [&](int bufi, int s) {
        const int kb = s * 128;
        #pragma unroll
        for (int i = 0; i < 4; ++i) {
            const int c = wave * 4 + i;
            if (c < 8) stage8(Wg + kb, Ws[bufi], c, lane);
            else       stage8(Xg + kb, Xs[bufi], c - 8, lane);
        }
    };

    f32x4 acc[2][2] = {};

    stage(0, 0);
    __syncthreads();

    for (int s = 0; s < 5; ++s) {
        const int bufi = s & 1;
        if (s + 1 < 5) stage(bufi ^ 1, s + 1);

        const char* ws = Ws[bufi];
        const char* xs = Xs[bufi];
        __builtin_amdgcn_s_setprio(1);
        #pragma unroll
        for (int ksub = 0; ksub < 2; ++ksub) {
            const int cb = ksub * 64 + lk * 16;
            const bf16x8 a0 = lds_frag(ws, wm * 32 + lr,      cb);
            const bf16x8 a1 = lds_frag(ws, wm * 32 + 16 + lr, cb);
            const bf16x8 b0 = lds_frag(xs, wn * 32 + lr,      cb);
            const bf16x8 b1 = lds_frag(xs, wn * 32 + 16 + lr, cb);
            acc[0][0] = MFMA16(a0, b0, acc[0][0]);
            acc[0][1] = MFMA16(a0, b1, acc[0][1]);
            acc[1][0] = MFMA16(a1, b0, acc[1][0]);
            acc[1][1] = MFMA16(a1, b1, acc[1][1]);
        }
        __builtin_amdgcn_s_setprio(0);
        __syncthreads();
    }

    #pragma unroll
    for (int am = 0; am < 2; ++am) {
        #pragma unroll
        for (int rp = 0; rp < 2; ++rp) {
            const int o = o0 + wm * 32 + am * 16 + 4 * lk + 2 * rp;
            const int h = o / DHEAD, d = o - h * DHEAD;
            const int bh = b * NHEADS + h;
            const float b0_ = bias[o], b1_ = bias[o + 1];
            #pragma unroll
            for (int bn = 0; bn < 2; ++bn) {
                const int n = n0 + wn * 32 + bn * 16 + lr;
                const float v0 = (acc[am][bn][2 * rp]     + b0_) * scale;
                const float v1 = (acc[am][bn][2 * rp + 1] + b1_) * scale;
                if (which < 2) {
                    __bf16* dst = ((which == 0) ? Qt : Kt)
                                + ((size_t)bh * N_SP + n) * DPAD + d;
                    bf16x2 t; t[0] = (__bf16)v0; t[1] = (__bf16)v1;
                    *(bf16x2*)dst = t;
                } else {
                    Vb[((size_t)bh * VPAD + d)     * N_SP + n] = (__bf16)v0;
                    Vb[((size_t)bh * VPAD + d + 1) * N_SP + n] = (__bf16)v1;
                }
            }
        }
    }
}

// -------------------------------------------------------------------------
// Output projection, LDS-staged, 32-wide o-tiles for occupancy.
// -------------------------------------------------------------------------
__global__ __launch_bounds__(256) void gemm_out32(
    const __bf16* __restrict__ Wob, const float* __restrict__ bo,
    const __bf16* __restrict__ att_t,
    float* __restrict__ Y, const float* __restrict__ resid)
{
    __shared__ __align__(16) char Ws[2][32 * 128];   // 2 x 4KB
    __shared__ __align__(16) char Xs[2][64 * 128];   // 2 x 8KB

    const int b = blockIdx.z;
    const int n0 = blockIdx.x * 64, o0 = blockIdx.y * 32;
    const int tid = threadIdx.x, wave = tid >> 6, lane = tid & 63;
    const int lr = lane & 15, lk = lane >> 4;
    const int wn = wave;

    const char* Wg = (const char*)(Wob + (size_t)o0 * C_DIM);
    const char* Xg = (const char*)(att_t + ((size_t)b * N_SP + n0) * C_DIM);

    auto stage = [&](int bufi, int s) {
        const int kb = s * 128;
        #pragma unroll
        for (int i = 0; i < 3; ++i) {
            const int c = wave * 3 + i;
            if (c < 4) stage8(Wg + kb, Ws[bufi], c, lane);
            else       stage8(Xg + kb, Xs[bufi], c - 4, lane);
        }
    };

    f32x4 acc[2] = {};

    stage(0, 0);
    __syncthreads();

    for (int s = 0; s < 5; ++s) {
        const int bufi = s & 1;
        if (s + 1 < 5) stage(bufi ^ 1, s + 1);

        const char* ws = Ws[bufi];
        const char* xs = Xs[bufi];
        __builtin_amdgcn_s_setprio(1);
        #pragma unroll
        for (int ksub = 0; ksub < 2; ++ksub) {
            const int cb = ksub * 64 + lk * 16;
            const bf16x8 a0 = lds_frag(ws, lr,      cb);
            const bf16x8 a1 = lds_frag(ws, 16 + lr, cb);
            const bf16x8 b0 = lds_frag(xs, wn * 16 + lr, cb);
            acc[0] = MFMA16(a0, b0, acc[0]);
            acc[1] = MFMA16(a1, b0, acc[1]);
        }
        __builtin_amdgcn_s_setprio(0);
        __syncthreads();
    }

    const int n = n0 + wn * 16 + lr;
    #pragma unroll
    for (int am = 0; am < 2; ++am) {
        #pragma unroll
        for (int r = 0; r < 4; ++r) {
            const int o = o0 + am * 16 + 4 * lk + r;
            const size_t idx = ((size_t)b * C_DIM + o) * N_SP + n;
            Y[idx] = acc[am][r] + bo[o] + resid[idx];
        }
    }
}

// -------------------------------------------------------------------------
// Flash attention, split-KV(6), KVBLK=32, no-max exp2 softmax, 32 q/wave,
// 4 waves/block. LDS = 19KB (Ks 2x4K swizzled, Vs 2x3K slot-swizzled,
// Ps 4x1.25K 80B-padded rows) -> 8 blocks/CU capacity; grid 1728 = 6.75/CU,
// all resident in ONE round at ~6.75 waves/SIMD.
// -------------------------------------------------------------------------
__global__ __launch_bounds__(256, 4) void attn_mfma(
    const __bf16* __restrict__ Qt,
    const __bf16* __restrict__ Kt,
    const __bf16* __restrict__ Vb,
    __bf16* __restrict__ part)
{
    __shared__ __align__(16) char Ks[2][KVBLK * 128];   // 2 x 4KB
    __shared__ __align__(16) char Vs[2][48 * 64];       // 2 x 3KB
    __shared__ __align__(16) char Ps[4][16 * 80];       // per-wave 1.25KB

    // XCD decode: [2:0]=bh>>1, [3]=bh&1; rest = qx*NSPLIT + s
    const int flat = blockIdx.x;
    const int bh = ((flat & 7) << 1) | ((flat >> 3) & 1);
    const int rest = flat >> 4;                 // 0..107
    const int qx = rest / NSPLIT;               // 0..17
    const int s  = rest - NSPLIT * qx;          // 0..5
    const int tid = threadIdx.x, wave = tid >> 6, lane = tid & 63;
    const int lr = lane & 15, lk = lane >> 4;
    const int swz = (lr & 7) << 4;              // K-tile XOR (128B rows)
    const int vslot = (lk ^ ((lr >> 1) & 3)) * 16;  // V-tile slot swizzle
    const int i0 = (qx * 4 + wave) * 32;

    const char* Kg = (const char*)(Kt + (size_t)bh * N_SP * DPAD);
    const char* Vg = (const char*)(Vb + (size_t)bh * VPAD * N_SP);

    bf16x8 qb[2][2];
    #pragma unroll
    for (int qh = 0; qh < 2; ++qh) {
        const __bf16* Qp = Qt + ((size_t)bh * N_SP + i0 + qh * 16 + lr) * DPAD + lk * 8;
        qb[qh][0] = *(const bf16x8*)(Qp);
        qb[qh][1] = *(const bf16x8*)(Qp + 32);
    }

    f32x4 O[2][3] = {};

    // per stage: K = 1 chunk per wave (4 chunks); V = 3 chunks (waves 0-2).
    auto stage = [&](char* kd, char* vd, int t) {
        const int j0 = t * KVBLK;
        {
            const int row = wave * 8 + (lane >> 3);
            const int cs  = (lane & 7) * 16;
            __builtin_amdgcn_global_load_lds(
                (gas_ptr)(Kg + (size_t)(j0 + row) * 128 + (cs ^ ((row & 7) << 4))),
                (las_ptr)(kd + wave * 1024 + lane * 16), 16, 0, 0);
        }
        if (wave < 3) {
            const int row = wave * 16 + (lane >> 2);
            const int sslot = (((lane & 3) ^ ((row >> 1) & 3)) * 16);
            __builtin_amdgcn_global_load_lds(
                (gas_ptr)(Vg + (size_t)row * (N_SP * 2) + (size_t)j0 * 2 + sslot),
                (las_ptr)(vd + wave * 1024 + lane * 16), 16, 0, 0);
        }
    };

    auto compute = [&](const char* ks, const char* vs) {
        char* ps = Ps[wave];

        // ---- S^T = K · Q (K frags shared by both q-halves) ----
        f32x4 S[2][2];
        __builtin_amdgcn_s_setprio(1);
        #pragma unroll
        for (int kt = 0; kt < 2; ++kt) {
            const int rowb = (kt * 16 + lr) * 128;
            const bf16x8 k0 = *(const bf16x8*)(ks + rowb + ((lk * 16) ^ swz));
            const bf16x8 k1 = *(const bf16x8*)(ks + rowb + ((64 + lk * 16) ^ swz));
            #pragma unroll
            for (int qh = 0; qh < 2; ++qh) {
                f32x4 zz = {};
                zz = MFMA16(k0, qb[qh][0], zz);
                S[qh][kt] = MFMA16(k1, qb[qh][1], zz);
            }
        }
        __builtin_amdgcn_s_setprio(0);

        // ---- V fragments into registers (read once per tile) ----
        bf16x8 va[3];
        #pragma unroll
        for (int dt = 0; dt < 3; ++dt)
            va[dt] = *(const bf16x8*)(vs + (dt * 16 + lr) * 64 + vslot);

        // ---- per half: P = exp2(S) -> Ps, then 3 PV MFMAs ----
        #pragma unroll
        for (int qh = 0; qh < 2; ++qh) {
            #pragma unroll
            for (int kt = 0; kt < 2; ++kt) {
                bf16x4 w;
                #pragma unroll
                for (int r = 0; r < 4; ++r)
                    w[r] = (__bf16)EXP2(S[qh][kt][r]);
                *(bf16x4*)(ps + lr * 80 + kt * 32 + lk * 8) = w;
            }
            __builtin_amdgcn_s_setprio(1);
            const bf16x8 pb = *(const bf16x8*)(ps + lr * 80 + lk * 16);
            #pragma unroll
            for (int dt = 0; dt < 3; ++dt)
                O[qh][dt] = MFMA16(va[dt], pb, O[qh][dt]);
            __builtin_amdgcn_s_setprio(0);
        }
    };

    const int t0 = s * TILES_PER_SPLIT;

    stage(Ks[0], Vs[0], t0);

    #pragma unroll 1
    for (int tt = 0; tt < TILES_PER_SPLIT; tt += 2) {
        {
            stage(Ks[1], Vs[1], t0 + tt + 1);
            if (wave < 3) asm volatile("s_waitcnt vmcnt(2)" ::: "memory");
            else          asm volatile("s_waitcnt vmcnt(1)" ::: "memory");
            __builtin_amdgcn_s_barrier();
            compute(Ks[0], Vs[0]);
            __builtin_amdgcn_s_barrier();
        }
        {
            if (tt + 2 < TILES_PER_SPLIT) {
                stage(Ks[0], Vs[0], t0 + tt + 2);
                if (wave < 3) asm volatile("s_waitcnt vmcnt(2)" ::: "memory");
                else          asm volatile("s_waitcnt vmcnt(1)" ::: "memory");
            } else {
                asm volatile("s_waitcnt vmcnt(0)" ::: "memory");
            }
            __builtin_amdgcn_s_barrier();
            compute(Ks[1], Vs[1]);
            __builtin_amdgcn_s_barrier();
        }
    }

    // ---- epilogue: bf16 partials for both halves ----
    #pragma unroll
    for (int qh = 0; qh < 2; ++qh) {
        __bf16* pq = part + ((size_t)(s * 16 + bh) * PSLOTS) * N_SP + (i0 + qh * 16 + lr);
        #pragma unroll
        for (int dt = 0; dt < 3; ++dt) {
            #pragma unroll
            for (int r = 0; r < 4; ++r) {
                const int d = dt * 16 + 4 * lk + r;
                if (d < 40) pq[(size_t)d * N_SP] = (__bf16)O[qh][dt][r];
            }
        }
        if (lk == 2) pq[(size_t)40 * N_SP] = (__bf16)O[qh][2][0];
    }
}

// -------------------------------------------------------------------------
// Combine the six KV-split partials (bf16) -> att_t [B][N][320] bf16.
// grid (36, 16) x 256: thread = (q = 64 lanes, d-group = 4).
// -------------------------------------------------------------------------
__global__ __launch_bounds__(256) void attn_combine(
    const __bf16* __restrict__ part, __bf16* __restrict__ att_t)
{
    const int q  = blockIdx.x * 64 + (threadIdx.x & 63);
    const int dg = threadIdx.x >> 6;            // 0..3
    const int bh = blockIdx.y, b = bh >> 3, h = bh & 7;

    const __bf16* p[NSPLIT];
    float l = 0.f;
    #pragma unroll
    for (int s = 0; s < NSPLIT; ++s) {
        p[s] = part + ((size_t)(s * 16 + bh) * PSLOTS) * N_SP + q;
        l += (float)p[s][(size_t)40 * N_SP];
    }
    const float inv = 1.0f / l;

    __bf16* op = att_t + ((size_t)b * N_SP + q) * C_DIM + h * DHEAD + dg * 10;
    #pragma unroll
    for (int d = 0; d < 10; d += 2) {
        float a0 = 0.f, a1 = 0.f;
        #pragma unroll
        for (int s = 0; s < NSPLIT; ++s) {
            a0 += (float)p[s][(size_t)(dg * 10 + d)     * N_SP];
            a1 += (float)p[s][(size_t)(dg * 10 + d + 1) * N_SP];
        }
        bf16x2 t;
        t[0] = (__bf16)(a0 * inv);
        t[1] = (__bf16)(a1 * inv);
        *(bf16x2*)(op + d) = t;
    }
}

// -------------------------------------------------------------------------
extern "C" void kernel_launch(void* const* d_in, const int* in_sizes, int n_in,
                              void* d_out, int out_size, void* d_ws, size_t ws_size,
                              hipStream_t stream) {
    const float* x     = (const float*)d_in[0];
    const float* gamma = (const float*)d_in[1];
    const float* beta  = (const float*)d_in[2];
    const float* Wq    = (const float*)d_in[3];
    const float* bq    = (const float*)d_in[4];
    const float* Wk    = (const float*)d_in[5];
    const float* bk    = (const float*)d_in[6];
    const float* Wv    = (const float*)d_in[7];
    const float* bv    = (const float*)d_in[8];
    const float* Wo    = (const float*)d_in[9];
    const float* bo    = (const float*)d_in[10];

    float* out = (float*)d_out;

    const size_t S_NC  = (size_t)BATCH * N_SP * C_DIM;          // 1,474,560
    const size_t S_QK  = (size_t)BATCH * NHEADS * N_SP * DPAD;  // 2,359,296
    const size_t S_V   = (size_t)BATCH * NHEADS * VPAD * N_SP;  // 1,769,472

    __bf16* xn_t  = (__bf16*)d_ws;
    __bf16* Qt    = xn_t + S_NC;
    __bf16* Kt    = Qt + S_QK;
    __bf16* Vb    = Kt + S_QK;
    __bf16* att_t = Vb + S_V;
    __bf16* Wqb   = att_t + S_NC;
    __bf16* Wkb   = Wqb + W_ELEMS;
    __bf16* Wvb   = Wkb + W_ELEMS;
    __bf16* Wob   = Wvb + W_ELEMS;
    float* partials = (float*)(Wob + W_ELEMS);           // 1024 floats
    __bf16* part    = (__bf16*)(partials + 1024);        // NSPLIT*16*41*2304 bf16

    prep_kernel<<<756, 256, 0, stream>>>(
        x, partials, Wq, Wk, Wv, Wo, Wqb, Wkb, Wvb, Wob, Qt, Kt, Vb);

    gn_apply<<<512, 256, 0, stream>>>(x, gamma, beta, partials, xn_t);

    gemm_qkv<<<dim3(N_SP / 64, C_DIM / 64, 3 * BATCH), 256, 0, stream>>>(
        Wqb, Wkb, Wvb, bq, bk, bv, xn_t, Qt, Kt, Vb);

    attn_mfma<<<dim3(18 * 16 * NSPLIT), 256, 0, stream>>>(Qt, Kt, Vb, part);

    attn_combine<<<dim3(N_SP / 64, BATCH * NHEADS), 256, 0, stream>>>(part, att_t);

    gemm_out32<<<dim3(N_SP / 64, C_DIM / 32, BATCH), 256, 0, stream>>>(
        Wob, bo, att_t, out, x);
}

// Round 19
// 67.375 us; speedup vs baseline: 1.0172x; 1.0172x over previous
//
#include <hip/hip_runtime.h>
#include <hip/hip_bf16.h>

#define C_DIM   320
#define N_SP    2304      // 48*48
#define NHEADS  8
#define DHEAD   40
#define GROUPS  32
#define CPG     10
#define BATCH   2
#define DPAD    64        // d padded for K=32 MFMA steps
#define VPAD    48        // v rows padded to 3x16 (row 40 = ones, 41..47 = 0)
#define W_ELEMS (C_DIM * C_DIM)   // 102400
#define NSPLIT  3
#define TILES_PER_SPLIT 12        // 36 KV tiles / NSPLIT (EVEN -> 2x unroll)
#define PSLOTS  41                // 40 O + lsum (slot 40, produced by ones-row MFMA)

typedef __bf16 bf16x8 __attribute__((ext_vector_type(8)));
typedef __bf16 bf16x4 __attribute__((ext_vector_type(4)));
typedef __bf16 bf16x2 __attribute__((ext_vector_type(2)));
typedef float  f32x4  __attribute__((ext_vector_type(4)));

typedef const __attribute__((address_space(1))) void* gas_ptr;
typedef __attribute__((address_space(3))) void* las_ptr;

#define MFMA16(a, b, c) __builtin_amdgcn_mfma_f32_16x16x32_bf16((a), (b), (c), 0, 0, 0)

// Native 2^x: one v_exp_f32, no libm denormal fixups (|S| <= ~6 here).
#if __has_builtin(__builtin_amdgcn_exp2f)
#define EXP2(x) __builtin_amdgcn_exp2f(x)
#else
#define EXP2(x) __expf((x) * 0.6931471805599453f)
#endif

// -------------------------------------------------------------------------
// Staging helpers for 64-col bf16 tiles (row stride 640B in global).
// -------------------------------------------------------------------------
__device__ __forceinline__ void stage8(const char* gbase, char* lbase,
                                       int chunk, int lane)
{
    const int row = chunk * 8 + (lane >> 3);
    const int cs  = (lane & 7) * 16;
    __builtin_amdgcn_global_load_lds(
        (gas_ptr)(gbase + (size_t)row * (C_DIM * 2) + (cs ^ ((row & 7) << 4))),
        (las_ptr)(lbase + chunk * 1024 + lane * 16), 16, 0, 0);
}

__device__ __forceinline__ bf16x8 lds_frag(const char* lbase, int row, int cbyte)
{
    return *(const bf16x8*)(lbase + row * 128 + (cbyte ^ ((row & 7) << 4)));
}

// -------------------------------------------------------------------------
// prep: gn_part (0..511) + weight cvt (512..611) + Q/K/V pad init (612..755).
// -------------------------------------------------------------------------
__global__ __launch_bounds__(256) void prep_kernel(
    const float* __restrict__ x, float* __restrict__ partials,
    const float* __restrict__ Wq, const float* __restrict__ Wk,
    const float* __restrict__ Wv, const float* __restrict__ Wo,
    __bf16* __restrict__ Wqb, __bf16* __restrict__ Wkb,
    __bf16* __restrict__ Wvb, __bf16* __restrict__ Wob,
    __bf16* __restrict__ Qt, __bf16* __restrict__ Kt, __bf16* __restrict__ Vb)
{
    if (blockIdx.x < 512) {
        const int bid = blockIdx.x;
        const int bg = bid >> 3, p = bid & 7;
        const int b = bg >> 5, g = bg & 31;
        const float* xp = x + ((size_t)b * C_DIM + g * CPG) * N_SP + p * 288;
        const int tid = threadIdx.x;

        float sum = 0.f, sq = 0.f;
        #pragma unroll
        for (int c = 0; c < CPG; ++c) {
            for (int nl = tid; nl < 288; nl += 256) {
                const float v = xp[(size_t)c * N_SP + nl];
                sum += v; sq += v * v;
            }
        }
        #pragma unroll
        for (int off = 32; off; off >>= 1) {
            sum += __shfl_xor(sum, off);
            sq  += __shfl_xor(sq, off);
        }
        __shared__ float red[2][4];
        if ((tid & 63) == 0) { red[0][tid >> 6] = sum; red[1][tid >> 6] = sq; }
        __syncthreads();
        if (tid == 0) {
            partials[2 * bid]     = red[0][0] + red[0][1] + red[0][2] + red[0][3];
            partials[2 * bid + 1] = red[1][0] + red[1][1] + red[1][2] + red[1][3];
        }
    } else if (blockIdx.x < 612) {
        const int i = ((blockIdx.x - 512) * 256 + threadIdx.x) * 4;
        f32x4 a;
        bf16x4 o;
        a = *(const f32x4*)(Wq + i);
        #pragma unroll
        for (int e = 0; e < 4; ++e) o[e] = (__bf16)a[e];
        *(bf16x4*)(Wqb + i) = o;
        a = *(const f32x4*)(Wk + i);
        #pragma unroll
        for (int e = 0; e < 4; ++e) o[e] = (__bf16)a[e];
        *(bf16x4*)(Wkb + i) = o;
        a = *(const f32x4*)(Wv + i);
        #pragma unroll
        for (int e = 0; e < 4; ++e) o[e] = (__bf16)a[e];
        *(bf16x4*)(Wvb + i) = o;
        a = *(const f32x4*)(Wo + i);
        #pragma unroll
        for (int e = 0; e < 4; ++e) o[e] = (__bf16)a[e];
        *(bf16x4*)(Wob + i) = o;
    } else {
        const int t = (blockIdx.x - 612) * 256 + threadIdx.x;  // < 36864
        const bf16x8 z = {};
        __bf16* q = Qt + (size_t)t * DPAD + 40;
        __bf16* k = Kt + (size_t)t * DPAD + 40;
        *(bf16x8*)(q) = z; *(bf16x8*)(q + 8) = z; *(bf16x8*)(q + 16) = z;
        *(bf16x8*)(k) = z; *(bf16x8*)(k + 8) = z; *(bf16x8*)(k + 16) = z;
        const int bh = t / N_SP;
        const int rem = t - bh * N_SP;
        const int r = rem / 288, n8 = rem - r * 288;
        bf16x8 v = z;
        if (r == 0) {
            #pragma unroll
            for (int e = 0; e < 8; ++e) v[e] = (__bf16)1.0f;
        }
        *(bf16x8*)(Vb + ((size_t)bh * VPAD + 40 + r) * N_SP + n8 * 8) = v;
    }
}

// -------------------------------------------------------------------------
// GroupNorm pass 2: finalize + normalize + transposed bf16 write.
// -------------------------------------------------------------------------
__global__ __launch_bounds__(256) void gn_apply(
    const float* __restrict__ x,
    const float* __restrict__ gamma, const float* __restrict__ beta,
    const float* __restrict__ partials, __bf16* __restrict__ xn_t)
{
    const int bid = blockIdx.x;
    const int bg = bid >> 3, p = bid & 7;
    const int b = bg >> 5, g = bg & 31;
    const int c0 = g * CPG;

    float sum = 0.f, sq = 0.f;
    #pragma unroll
    for (int i = 0; i < 8; ++i) {
        sum += partials[(bg * 8 + i) * 2];
        sq  += partials[(bg * 8 + i) * 2 + 1];
    }
    const float inv_n = 1.0f / (float)(CPG * N_SP);
    const float mean = sum * inv_n;
    const float rstd = rsqrtf(sq * inv_n - mean * mean + 1e-5f);

    float ga[CPG], be[CPG];
    #pragma unroll
    for (int c = 0; c < CPG; ++c) {
        ga[c] = gamma[c0 + c] * rstd;
        be[c] = beta[c0 + c] - mean * ga[c];
    }

    const float* xp = x + ((size_t)b * C_DIM + c0) * N_SP + p * 288;
    for (int nl = threadIdx.x; nl < 288; nl += 256) {
        const int n = p * 288 + nl;
        __bf16* dst = xn_t + ((size_t)b * N_SP + n) * C_DIM + c0;
        #pragma unroll
        for (int j = 0; j < CPG / 2; ++j) {
            const float v0 = xp[(size_t)(2 * j) * N_SP + nl]     * ga[2 * j]     + be[2 * j];
            const float v1 = xp[(size_t)(2 * j + 1) * N_SP + nl] * ga[2 * j + 1] + be[2 * j + 1];
            bf16x2 t; t[0] = (__bf16)v0; t[1] = (__bf16)v1;
            *(bf16x2*)(dst + 2 * j) = t;
        }
    }
}

// -------------------------------------------------------------------------
// Fused QKV projection, LDS-staged, counted-vmcnt raw-barrier pipeline.
// -------------------------------------------------------------------------
__global__ __launch_bounds__(256) void gemm_qkv(
    const __bf16* __restrict__ Wqb, const __bf16* __restrict__ Wkb, const __bf16* __restrict__ Wvb,
    const float* __restrict__ bq, const float* __restrict__ bk, const float* __restrict__ bv,
    const __bf16* __restrict__ Xt,
    __bf16* __restrict__ Qt, __bf16* __restrict__ Kt, __bf16* __restrict__ Vb)
{
    __shared__ __align__(16) char Ws[2][64 * 128];   // 2 x 8KB
    __shared__ __align__(16) char Xs[2][64 * 128];   // 2 x 8KB

    const int z = blockIdx.z;
    const int b = z / 3;
    const int which = z - 3 * b;
    const __bf16* W   = (which == 0) ? Wqb : (which == 1) ? Wkb : Wvb;
    const float* bias = (which == 0) ? bq : (which == 1) ? bk : bv;
    const float scale = (which == 0) ? 0.15811388300841897f
                      : (which == 1) ? 0.22811243f : 1.0f;

    const int n0 = blockIdx.x * 64, o0 = blockIdx.y * 64;
    const int tid = threadIdx.x, wave = tid >> 6, lane = tid & 63;
    const int lr = lane & 15, lk = lane >> 4;
    const int wm = wave >> 1, wn = wave & 1;

    const char* Wg = (const char*)(W + (size_t)o0 * C_DIM);
    const char* Xg = (const char*)(Xt + ((size_t)b * N_SP + n0) * C_DIM);

    // each wave issues exactly 4 loads per stage
    auto stage = [&](int bufi, int s) {
        const int kb = s * 128;
        #pragma unroll
        for (int i = 0; i < 4; ++i) {
            const int c = wave * 4 + i;
            if (c < 8) stage8(Wg + kb, Ws[bufi], c, lane);
            else       stage8(Xg + kb, Xs[bufi], c - 8, lane);
        }
    };

    f32x4 acc[2][2] = {};

    stage(0, 0);

    for (int s = 0; s < 5; ++s) {
        const int bufi = s & 1;
        if (s + 1 < 5) {
            stage(bufi ^ 1, s + 1);
            asm volatile("s_waitcnt vmcnt(4)" ::: "memory");
        } else {
            asm volatile("s_waitcnt vmcnt(0)" ::: "memory");
        }
        __builtin_amdgcn_s_barrier();

        const char* ws = Ws[bufi];
        const char* xs = Xs[bufi];
        __builtin_amdgcn_s_setprio(1);
        #pragma unroll
        for (int ksub = 0; ksub < 2; ++ksub) {
            const int cb = ksub * 64 + lk * 16;
            const bf16x8 a0 = lds_frag(ws, wm * 32 + lr,      cb);
            const bf16x8 a1 = lds_frag(ws, wm * 32 + 16 + lr, cb);
            const bf16x8 b0 = lds_frag(xs, wn * 32 + lr,      cb);
            const bf16x8 b1 = lds_frag(xs, wn * 32 + 16 + lr, cb);
            acc[0][0] = MFMA16(a0, b0, acc[0][0]);
            acc[0][1] = MFMA16(a0, b1, acc[0][1]);
            acc[1][0] = MFMA16(a1, b0, acc[1][0]);
            acc[1][1] = MFMA16(a1, b1, acc[1][1]);
        }
        __builtin_amdgcn_s_setprio(0);
        __builtin_amdgcn_s_barrier();
    }

    #pragma unroll
    for (int am = 0; am < 2; ++am) {
        #pragma unroll
        for (int rp = 0; rp < 2; ++rp) {
            const int o = o0 + wm * 32 + am * 16 + 4 * lk + 2 * rp;
            const int h = o / DHEAD, d = o - h * DHEAD;
            const int bh = b * NHEADS + h;
            const float b0_ = bias[o], b1_ = bias[o + 1];
            #pragma unroll
            for (int bn = 0; bn < 2; ++bn) {
                const int n = n0 + wn * 32 + bn * 16 + lr;
                const float v0 = (acc[am][bn][2 * rp]     + b0_) * scale;
                const float v1 = (acc[am][bn][2 * rp + 1] + b1_) * scale;
                if (which < 2) {
                    __bf16* dst = ((which == 0) ? Qt : Kt)
                                + ((size_t)bh * N_SP + n) * DPAD + d;
                    bf16x2 t; t[0] = (__bf16)v0; t[1] = (__bf16)v1;
                    *(bf16x2*)dst = t;
                } else {
                    Vb[((size_t)bh * VPAD + d)     * N_SP + n] = (__bf16)v0;
                    Vb[((size_t)bh * VPAD + d + 1) * N_SP + n] = (__bf16)v1;
                }
            }
        }
    }
}

// -------------------------------------------------------------------------
// Output projection, LDS-staged, counted-vmcnt raw-barrier pipeline.
// -------------------------------------------------------------------------
__global__ __launch_bounds__(256) void gemm_out32(
    const __bf16* __restrict__ Wob, const float* __restrict__ bo,
    const __bf16* __restrict__ att_t,
    float* __restrict__ Y, const float* __restrict__ resid)
{
    __shared__ __align__(16) char Ws[2][32 * 128];   // 2 x 4KB
    __shared__ __align__(16) char Xs[2][64 * 128];   // 2 x 8KB

    const int b = blockIdx.z;
    const int n0 = blockIdx.x * 64, o0 = blockIdx.y * 32;
    const int tid = threadIdx.x, wave = tid >> 6, lane = tid & 63;
    const int lr = lane & 15, lk = lane >> 4;
    const int wn = wave;

    const char* Wg = (const char*)(Wob + (size_t)o0 * C_DIM);
    const char* Xg = (const char*)(att_t + ((size_t)b * N_SP + n0) * C_DIM);

    // each wave issues exactly 3 loads per stage
    auto stage = [&](int bufi, int s) {
        const int kb = s * 128;
        #pragma unroll
        for (int i = 0; i < 3; ++i) {
            const int c = wave * 3 + i;
            if (c < 4) stage8(Wg + kb, Ws[bufi], c, lane);
            else       stage8(Xg + kb, Xs[bufi], c - 4, lane);
        }
    };

    f32x4 acc[2] = {};

    stage(0, 0);

    for (int s = 0; s < 5; ++s) {
        const int bufi = s & 1;
        if (s + 1 < 5) {
            stage(bufi ^ 1, s + 1);
            asm volatile("s_waitcnt vmcnt(3)" ::: "memory");
        } else {
            asm volatile("s_waitcnt vmcnt(0)" ::: "memory");
        }
        __builtin_amdgcn_s_barrier();

        const char* ws = Ws[bufi];
        const char* xs = Xs[bufi];
        __builtin_amdgcn_s_setprio(1);
        #pragma unroll
        for (int ksub = 0; ksub < 2; ++ksub) {
            const int cb = ksub * 64 + lk * 16;
            const bf16x8 a0 = lds_frag(ws, lr,      cb);
            const bf16x8 a1 = lds_frag(ws, 16 + lr, cb);
            const bf16x8 b0 = lds_frag(xs, wn * 16 + lr, cb);
            acc[0] = MFMA16(a0, b0, acc[0]);
            acc[1] = MFMA16(a1, b0, acc[1]);
        }
        __builtin_amdgcn_s_setprio(0);
        __builtin_amdgcn_s_barrier();
    }

    const int n = n0 + wn * 16 + lr;
    #pragma unroll
    for (int am = 0; am < 2; ++am) {
        #pragma unroll
        for (int r = 0; r < 4; ++r) {
            const int o = o0 + am * 16 + 4 * lk + r;
            const size_t idx = ((size_t)b * C_DIM + o) * N_SP + n;
            Y[idx] = acc[am][r] + bo[o] + resid[idx];
        }
    }
}

// -------------------------------------------------------------------------
// Flash attention (r17 config): split-KV(3), KVBLK=64, no-max exp2 softmax,
// 32 q/wave, 4 waves/block, grid 864 single-round, counted-vmcnt pipeline.
// -------------------------------------------------------------------------
__global__ __launch_bounds__(256, 4) void attn_mfma(
    const __bf16* __restrict__ Qt,
    const __bf16* __restrict__ Kt,
    const __bf16* __restrict__ Vb,
    __bf16* __restrict__ part)
{
    __shared__ __align__(16) __bf16 Ks[2][64 * DPAD];   // 2 x 8KB
    __shared__ __align__(16) __bf16 Vs[2][VPAD * 64];   // 2 x 6KB
    __shared__ __align__(16) __bf16 Ps[4][16 * 64];     // per-wave P^T (2KB)

    // XCD decode: [2:0]=bh>>1, [3]=bh&1; rest = qx*3 + s
    const int flat = blockIdx.x;
    const int bh = ((flat & 7) << 1) | ((flat >> 3) & 1);
    const int rest = flat >> 4;                 // 0..53
    const int qx = rest / 3;                    // 0..17
    const int s  = rest - 3 * qx;               // 0..2
    const int tid = threadIdx.x, wave = tid >> 6, lane = tid & 63;
    const int lr = lane & 15, lk = lane >> 4;
    const int swz = (lr & 7) << 4;
    const int i0 = (qx * 4 + wave) * 32;

    const char* Kg = (const char*)(Kt + (size_t)bh * N_SP * DPAD);
    const char* Vg = (const char*)(Vb + (size_t)bh * VPAD * N_SP);

    bf16x8 qb[2][2];
    #pragma unroll
    for (int qh = 0; qh < 2; ++qh) {
        const __bf16* Qp = Qt + ((size_t)bh * N_SP + i0 + qh * 16 + lr) * DPAD + lk * 8;
        qb[qh][0] = *(const bf16x8*)(Qp);
        qb[qh][1] = *(const bf16x8*)(Qp + 32);
    }

    f32x4 O[2][3] = {};

    auto stage = [&](char* kd, char* vd, int t) {
        const int j0 = t * 64;
        #pragma unroll
        for (int i2 = 0; i2 < 2; ++i2) {
            const int chunk = wave * 2 + i2;
            const int L = chunk * 1024 + lane * 16;
            const int src = L ^ (((L >> 7) & 7) << 4);
            __builtin_amdgcn_global_load_lds(
                (gas_ptr)(Kg + (size_t)j0 * 128 + src),
                (las_ptr)(kd + chunk * 1024), 16, 0, 0);
        }
        for (int i2 = wave; i2 < 6; i2 += 4) {
            const int row = i2 * 8 + (lane >> 3);
            const int csw = ((lane & 7) << 4) ^ ((row & 7) << 4);
            __builtin_amdgcn_global_load_lds(
                (gas_ptr)(Vg + ((size_t)row * N_SP + j0) * 2 + csw),
                (las_ptr)(vd + i2 * 1024), 16, 0, 0);
        }
    };

    auto compute = [&](const char* ks, const char* vs) {
        char* ps = (char*)Ps[wave];

        // S^T = K · Q (K frags shared by both q-halves)
        f32x4 S[2][4];
        __builtin_amdgcn_s_setprio(1);
        #pragma unroll
        for (int kt = 0; kt < 4; ++kt) {
            const int rowb = (kt * 16 + lr) * 128;
            const bf16x8 k0 = *(const bf16x8*)(ks + rowb + ((lk * 16) ^ swz));
            const bf16x8 k1 = *(const bf16x8*)(ks + rowb + ((64 + lk * 16) ^ swz));
            #pragma unroll
            for (int qh = 0; qh < 2; ++qh) {
                f32x4 zz = {};
                zz = MFMA16(k0, qb[qh][0], zz);
                S[qh][kt] = MFMA16(k1, qb[qh][1], zz);
            }
        }
        __builtin_amdgcn_s_setprio(0);

        // V fragments into registers (read once per tile)
        bf16x8 va[2][3];
        #pragma unroll
        for (int hh = 0; hh < 2; ++hh)
            #pragma unroll
            for (int dt = 0; dt < 3; ++dt)
                va[hh][dt] = *(const bf16x8*)(vs + (dt * 16 + lr) * 128
                                              + ((hh * 64 + lk * 16) ^ swz));

        // per half: P = exp2(S) -> Ps (2KB reused), then 6 PV MFMAs
        #pragma unroll
        for (int qh = 0; qh < 2; ++qh) {
            #pragma unroll
            for (int kt = 0; kt < 4; ++kt) {
                bf16x4 w;
                #pragma unroll
                for (int r = 0; r < 4; ++r)
                    w[r] = (__bf16)EXP2(S[qh][kt][r]);
                *(bf16x4*)(ps + lr * 128 + ((kt * 32 + lk * 8) ^ swz)) = w;
            }
            __builtin_amdgcn_s_setprio(1);
            #pragma unroll
            for (int hh = 0; hh < 2; ++hh) {
                const bf16x8 pb = *(const bf16x8*)(ps + lr * 128 + ((hh * 64 + lk * 16) ^ swz));
                #pragma unroll
                for (int dt = 0; dt < 3; ++dt)
                    O[qh][dt] = MFMA16(va[hh][dt], pb, O[qh][dt]);
            }
            __builtin_amdgcn_s_setprio(0);
        }
    };

    const int t0 = s * TILES_PER_SPLIT;

    stage((char*)Ks[0], (char*)Vs[0], t0);

    #pragma unroll 1
    for (int tt = 0; tt < TILES_PER_SPLIT; tt += 2) {
        {
            stage((char*)Ks[1], (char*)Vs[1], t0 + tt + 1);
            if (wave < 2) asm volatile("s_waitcnt vmcnt(4)" ::: "memory");
            else          asm volatile("s_waitcnt vmcnt(3)" ::: "memory");
            __builtin_amdgcn_s_barrier();
            compute((const char*)Ks[0], (const char*)Vs[0]);
            __builtin_amdgcn_s_barrier();
        }
        {
            if (tt + 2 < TILES_PER_SPLIT) {
                stage((char*)Ks[0], (char*)Vs[0], t0 + tt + 2);
                if (wave < 2) asm volatile("s_waitcnt vmcnt(4)" ::: "memory");
                else          asm volatile("s_waitcnt vmcnt(3)" ::: "memory");
            } else {
                asm volatile("s_waitcnt vmcnt(0)" ::: "memory");
            }
            __builtin_amdgcn_s_barrier();
            compute((const char*)Ks[1], (const char*)Vs[1]);
            __builtin_amdgcn_s_barrier();
        }
    }

    // ---- epilogue: bf16 partials for both halves ----
    #pragma unroll
    for (int qh = 0; qh < 2; ++qh) {
        __bf16* pq = part + ((size_t)(s * 16 + bh) * PSLOTS) * N_SP + (i0 + qh * 16 + lr);
        #pragma unroll
        for (int dt = 0; dt < 3; ++dt) {
            #pragma unroll
            for (int r = 0; r < 4; ++r) {
                const int d = dt * 16 + 4 * lk + r;
                if (d < 40) pq[(size_t)d * N_SP] = (__bf16)O[qh][dt][r];
            }
        }
        if (lk == 2) pq[(size_t)40 * N_SP] = (__bf16)O[qh][2][0];
    }
}

// -------------------------------------------------------------------------
// Combine the three KV-split partials (bf16) -> att_t [B][N][320] bf16.
// grid (36, 16) x 256: thread = (q = 64 lanes, d-group = 4).
// -------------------------------------------------------------------------
__global__ __launch_bounds__(256) void attn_combine(
    const __bf16* __restrict__ part, __bf16* __restrict__ att_t)
{
    const int q  = blockIdx.x * 64 + (threadIdx.x & 63);
    const int dg = threadIdx.x >> 6;            // 0..3
    const int bh = blockIdx.y, b = bh >> 3, h = bh & 7;

    const __bf16* p[NSPLIT];
    float l = 0.f;
    #pragma unroll
    for (int s = 0; s < NSPLIT; ++s) {
        p[s] = part + ((size_t)(s * 16 + bh) * PSLOTS) * N_SP + q;
        l += (float)p[s][(size_t)40 * N_SP];
    }
    const float inv = 1.0f / l;

    __bf16* op = att_t + ((size_t)b * N_SP + q) * C_DIM + h * DHEAD + dg * 10;
    #pragma unroll
    for (int d = 0; d < 10; d += 2) {
        float a0 = 0.f, a1 = 0.f;
        #pragma unroll
        for (int s = 0; s < NSPLIT; ++s) {
            a0 += (float)p[s][(size_t)(dg * 10 + d)     * N_SP];
            a1 += (float)p[s][(size_t)(dg * 10 + d + 1) * N_SP];
        }
        bf16x2 t;
        t[0] = (__bf16)(a0 * inv);
        t[1] = (__bf16)(a1 * inv);
        *(bf16x2*)(op + d) = t;
    }
}

// -------------------------------------------------------------------------
extern "C" void kernel_launch(void* const* d_in, const int* in_sizes, int n_in,
                              void* d_out, int out_size, void* d_ws, size_t ws_size,
                              hipStream_t stream) {
    const float* x     = (const float*)d_in[0];
    const float* gamma = (const float*)d_in[1];
    const float* beta  = (const float*)d_in[2];
    const float* Wq    = (const float*)d_in[3];
    const float* bq    = (const float*)d_in[4];
    const float* Wk    = (const float*)d_in[5];
    const float* bk    = (const float*)d_in[6];
    const float* Wv    = (const float*)d_in[7];
    const float* bv    = (const float*)d_in[8];
    const float* Wo    = (const float*)d_in[9];
    const float* bo    = (const float*)d_in[10];

    float* out = (float*)d_out;

    const size_t S_NC  = (size_t)BATCH * N_SP * C_DIM;          // 1,474,560
    const size_t S_QK  = (size_t)BATCH * NHEADS * N_SP * DPAD;  // 2,359,296
    const size_t S_V   = (size_t)BATCH * NHEADS * VPAD * N_SP;  // 1,769,472

    __bf16* xn_t  = (__bf16*)d_ws;
    __bf16* Qt    = xn_t + S_NC;
    __bf16* Kt    = Qt + S_QK;
    __bf16* Vb    = Kt + S_QK;
    __bf16* att_t = Vb + S_V;
    __bf16* Wqb   = att_t + S_NC;
    __bf16* Wkb   = Wqb + W_ELEMS;
    __bf16* Wvb   = Wkb + W_ELEMS;
    __bf16* Wob   = Wvb + W_ELEMS;
    float* partials = (float*)(Wob + W_ELEMS);           // 1024 floats
    __bf16* part    = (__bf16*)(partials + 1024);        // NSPLIT*16*41*2304 bf16

    prep_kernel<<<756, 256, 0, stream>>>(
        x, partials, Wq, Wk, Wv, Wo, Wqb, Wkb, Wvb, Wob, Qt, Kt, Vb);

    gn_apply<<<512, 256, 0, stream>>>(x, gamma, beta, partials, xn_t);

    gemm_qkv<<<dim3(N_SP / 64, C_DIM / 64, 3 * BATCH), 256, 0, stream>>>(
        Wqb, Wkb, Wvb, bq, bk, bv, xn_t, Qt, Kt, Vb);

    attn_mfma<<<dim3(18 * 16 * NSPLIT), 256, 0, stream>>>(Qt, Kt, Vb, part);

    attn_combine<<<dim3(N_SP / 64, BATCH * NHEADS), 256, 0, stream>>>(part, att_t);

    gemm_out32<<<dim3(N_SP / 64, C_DIM / 32, BATCH), 256, 0, stream>>>(
        Wob, bo, att_t, out, x);
}